// Round 5
// baseline (707.345 us; speedup 1.0000x reference)
//
#include <hip/hip_runtime.h>

#define DD 1024
#define HALO 32
#define IMG 1088                 // HALO+DD+HALO floats = 17*64 -> swizzle-compatible
#define HALF_DT_F 0.05f
#define CG_ITERS_N 20

// XOR swizzle on float index (byte' = byte ^ (((byte>>7)&1)<<4)).
// Involution; preserves 16B alignment; commutes with any offset that is a
// multiple of 64 floats (256B): IMG and +-DD qualify. Spreads this kernel's
// 32B-lane-stride float4 accesses across all 8 LDS bank groups.
__device__ __forceinline__ int swzf(int f) { return f ^ (((f >> 5) & 1) << 2); }

// Wave64 sum via DPP (pure VALU, no LDS pipe). Total valid in lane 63 ONLY.
__device__ __forceinline__ float dpp_wave_sum(float v) {
    int b;
    b = __builtin_amdgcn_update_dpp(0, __float_as_int(v), 0x111, 0xf, 0xf, true); v += __int_as_float(b); // row_shr:1
    b = __builtin_amdgcn_update_dpp(0, __float_as_int(v), 0x112, 0xf, 0xf, true); v += __int_as_float(b); // row_shr:2
    b = __builtin_amdgcn_update_dpp(0, __float_as_int(v), 0x114, 0xf, 0xf, true); v += __int_as_float(b); // row_shr:4
    b = __builtin_amdgcn_update_dpp(0, __float_as_int(v), 0x118, 0xf, 0xf, true); v += __int_as_float(b); // row_shr:8
    b = __builtin_amdgcn_update_dpp(0, __float_as_int(v), 0x142, 0xa, 0xf, true); v += __int_as_float(b); // row_bcast:15
    b = __builtin_amdgcn_update_dpp(0, __float_as_int(v), 0x143, 0xc, 0xf, true); v += __int_as_float(b); // row_bcast:31
    return v;
}

// H on this thread's 8 elements. Window = 48 floats [d0-20, d0+28); the 8
// center values come from this thread's registers -> 10 b128 LDS reads/comp.
__device__ __forceinline__ void hmat8(const float* lds, const int ra[10], int cOff,
                                      const float cw[11], const float diag[8],
                                      const float pc[8], float H[8]) {
    float win[48];
#pragma unroll
    for (int k = 0; k < 5; ++k) {
        float4 v = *reinterpret_cast<const float4*>(&lds[ra[k] + cOff]);
        win[4 * k + 0] = v.x; win[4 * k + 1] = v.y;
        win[4 * k + 2] = v.z; win[4 * k + 3] = v.w;
    }
#pragma unroll
    for (int i = 0; i < 8; ++i) win[20 + i] = pc[i];
#pragma unroll
    for (int k = 0; k < 5; ++k) {
        float4 v = *reinterpret_cast<const float4*>(&lds[ra[5 + k] + cOff]);
        win[28 + 4 * k + 0] = v.x; win[28 + 4 * k + 1] = v.y;
        win[28 + 4 * k + 2] = v.z; win[28 + 4 * k + 3] = v.w;
    }
    constexpr int taps[11] = {1, 2, 3, 4, 5, 6, 8, 10, 12, 16, 20};
#pragma unroll
    for (int i = 0; i < 8; ++i) {
        float acc = diag[i] * win[20 + i];
#pragma unroll
        for (int j = 0; j < 11; ++j)
            acc -= cw[j] * (win[20 + i - taps[j]] + win[20 + i + taps[j]]);
        H[i] = acc;
    }
}

// Store this thread's 8 elements (both components) + halo copies
// (threads 0..3 duplicate to the right halo, 124..127 to the left).
__device__ __forceinline__ void store_row8(float* lds, const int wa[2], const int ha[2],
                                           bool hh, const float vr[8], const float vi[8]) {
#pragma unroll
    for (int j = 0; j < 2; ++j) {
        float4 a = make_float4(vr[4 * j], vr[4 * j + 1], vr[4 * j + 2], vr[4 * j + 3]);
        float4 b = make_float4(vi[4 * j], vi[4 * j + 1], vi[4 * j + 2], vi[4 * j + 3]);
        *reinterpret_cast<float4*>(&lds[wa[j]]) = a;
        *reinterpret_cast<float4*>(&lds[wa[j] + IMG]) = b;
        if (hh) {
            *reinterpret_cast<float4*>(&lds[ha[j]]) = a;
            *reinterpret_cast<float4*>(&lds[ha[j] + IMG]) = b;
        }
    }
}

__global__ void __launch_bounds__(128, 3)
cayley_kernel(const float* __restrict__ psi_r, const float* __restrict__ psi_i,
              const float* __restrict__ alpha, const float* __restrict__ sw,
              const float* __restrict__ potential, float* __restrict__ out) {
    __shared__ __align__(16) float lds[2 * IMG];   // one row, both components
    __shared__ float red[4];                       // {rho, mu} per wave

    const int u = threadIdx.x;      // 0..127; owns elements [8u, 8u+8)
    const int wv = u >> 6;
    const int row = blockIdx.x;

    const float w0 = sw[0], w1 = sw[1], w2 = sw[2];   // uniform -> scalar loads
    const float cw[11] = {w0, w0 + w1, w0, w0 + w1 + w2, w0, w1, w1 + w2, w1, w2, w2, w2};
    const float dadd = 10.0f * (w0 + w1 + w2);

    // Loop-invariant swizzled LDS addresses (float indices, component 0).
    int wa[2], ra[10];
#pragma unroll
    for (int j = 0; j < 2; ++j) wa[j] = swzf(HALO + 8 * u + 4 * j);
#pragma unroll
    for (int k = 0; k < 5; ++k) {
        ra[k]     = swzf(HALO + 8 * u - 20 + 4 * k);   // left 20 floats
        ra[5 + k] = swzf(HALO + 8 * u + 8 + 4 * k);    // right 20 floats
    }
    const bool hh = (u < 4) || (u >= 124);
    int ha[2] = {0, 0};
    if (u < 4) {
#pragma unroll
        for (int j = 0; j < 2; ++j) ha[j] = swzf(HALO + 8 * u + DD + 4 * j);
    } else if (u >= 124) {
#pragma unroll
        for (int j = 0; j < 2; ++j) ha[j] = swzf(HALO + 8 * u - DD + 4 * j);
    }

    // --- global loads: 8 contiguous elements per thread ---
    const size_t goff = (size_t)row * DD + 8 * u;
    float rr[8], ri[8], diag[8];
#pragma unroll
    for (int j = 0; j < 2; ++j) {
        float4 a = *reinterpret_cast<const float4*>(psi_r + goff + 4 * j);
        float4 b = *reinterpret_cast<const float4*>(psi_i + goff + 4 * j);
        float4 d = *reinterpret_cast<const float4*>(potential + 8 * u + 4 * j);
        rr[4 * j] = a.x; rr[4 * j + 1] = a.y; rr[4 * j + 2] = a.z; rr[4 * j + 3] = a.w;
        ri[4 * j] = b.x; ri[4 * j + 1] = b.y; ri[4 * j + 2] = b.z; ri[4 * j + 3] = b.w;
        diag[4 * j] = d.x + dadd; diag[4 * j + 1] = d.y + dadd;
        diag[4 * j + 2] = d.z + dadd; diag[4 * j + 3] = d.w + dadd;
    }

    // --- intensity mean over the row ---
    float isum = 0.f;
#pragma unroll
    for (int i = 0; i < 8; ++i) isum += rr[i] * rr[i] + ri[i] * ri[i];
    isum = dpp_wave_sum(isum);
    if ((u & 63) == 63) red[wv] = isum;     // lane 63 holds wave total
    __syncthreads();
    const float inv_mean = 1.0f / ((red[0] + red[1]) * (1.0f / DD) + 1e-8f);

    // --- nonlinear phase rotation (in place) ---
#pragma unroll
    for (int j = 0; j < 2; ++j) {
        float4 c = *reinterpret_cast<const float4*>(alpha + 8 * u + 4 * j);
        float av[4] = {c.x, c.y, c.z, c.w};
#pragma unroll
        for (int q = 0; q < 4; ++q) {
            const int i = 4 * j + q;
            const float ph = av[q] * ((rr[i] * rr[i] + ri[i] * ri[i]) * inv_mean);
            float s, cc;
            sincosf(ph, &s, &cc);
            const float nr = rr[i] * cc - ri[i] * s;
            const float ni = rr[i] * s + ri[i] * cc;
            rr[i] = nr; ri[i] = ni;
        }
    }

    store_row8(lds, wa, ha, hh, rr, ri);    // rot image
    __syncthreads();

    // --- r = b = (I - i*h*H) rot ; x = 0 ; p = s = 0 (beta_0 = 0) ---
    float Hr[8], Hi[8];
    hmat8(lds, ra, 0, cw, diag, rr, Hr);
    hmat8(lds, ra, IMG, cw, diag, ri, Hi);

    float xr[8], xi[8], pr_[8], pi_[8], sr_[8], si_[8];
    float rho_part = 0.f;
#pragma unroll
    for (int i = 0; i < 8; ++i) {
        const float br = rr[i] + HALF_DT_F * Hi[i];
        const float bi = ri[i] - HALF_DT_F * Hr[i];
        rr[i] = br; ri[i] = bi;
        xr[i] = 0.f; xi[i] = 0.f; pr_[i] = 0.f; pi_[i] = 0.f; sr_[i] = 0.f; si_[i] = 0.f;
        rho_part += br * br + bi * bi;
    }
    __syncthreads();                        // all rot-window reads done
    store_row8(lds, wa, ha, hh, rr, ri);    // r image
    __syncthreads();

    // --- Chronopoulos-Gear CG: one fused reduction + one store fence per iter ---
    float rho_prev = 1.f, alpha_prev = 1.f;
#pragma unroll 1
    for (int it = 0; it < CG_ITERS_N; ++it) {
        // w = A r = (rr - h*H(ri), ri + h*H(rr))
        hmat8(lds, ra, 0, cw, diag, rr, Hr);
        hmat8(lds, ra, IMG, cw, diag, ri, Hi);
        float wr[8], wi[8];
        float mu_part = 0.f;
#pragma unroll
        for (int i = 0; i < 8; ++i) {
            wr[i] = rr[i] - HALF_DT_F * Hi[i];
            wi[i] = ri[i] + HALF_DT_F * Hr[i];
            mu_part += wr[i] * rr[i] + wi[i] * ri[i];
        }
        // fused reduction: rho (from prev update) and mu, two interleaved DPP chains
        const float rho_w = dpp_wave_sum(rho_part);
        const float mu_w = dpp_wave_sum(mu_part);
        if ((u & 63) == 63) { red[2 * wv] = rho_w; red[2 * wv + 1] = mu_w; }
        __syncthreads();                               // also fences window reads
        const float rho = red[0] + red[2];
        const float mu = red[1] + red[3];
        const float beta = (it == 0) ? 0.f : rho / (rho_prev + 1e-12f);
        const float pAp = mu - beta * rho / alpha_prev;
        const float al = rho / (pAp + 1e-12f);
        rho_prev = rho; alpha_prev = al;

        float rho_new = 0.f;
#pragma unroll
        for (int i = 0; i < 8; ++i) {
            pr_[i] = rr[i] + beta * pr_[i];
            pi_[i] = ri[i] + beta * pi_[i];
            sr_[i] = wr[i] + beta * sr_[i];
            si_[i] = wi[i] + beta * si_[i];
            xr[i] += al * pr_[i];
            xi[i] += al * pi_[i];
            rr[i] -= al * sr_[i];
            ri[i] -= al * si_[i];
            rho_new += rr[i] * rr[i] + ri[i] * ri[i];
        }
        rho_part = rho_new;

        if (it != CG_ITERS_N - 1) {
            store_row8(lds, wa, ha, hh, rr, ri);       // r image for next matvec
            __syncthreads();
        }
    }

    // --- write x as [.., D, 2] real pairs: 4 coalesced float4 per thread ---
    float* op = out + 2 * goff;
#pragma unroll
    for (int j = 0; j < 4; ++j) {
        *reinterpret_cast<float4*>(op + 4 * j) =
            make_float4(xr[2 * j], xi[2 * j], xr[2 * j + 1], xi[2 * j + 1]);
    }
}

extern "C" void kernel_launch(void* const* d_in, const int* in_sizes, int n_in,
                              void* d_out, int out_size, void* d_ws, size_t ws_size,
                              hipStream_t stream) {
    const float* psi_r = (const float*)d_in[0];
    const float* psi_i = (const float*)d_in[1];
    const float* alpha = (const float*)d_in[2];
    const float* sw = (const float*)d_in[3];
    const float* pot = (const float*)d_in[4];
    float* out = (float*)d_out;
    const int rows = in_sizes[0] / DD;   // B*S = 8192
    cayley_kernel<<<dim3(rows), dim3(128), 0, stream>>>(psi_r, psi_i, alpha, sw, pot, out);
}

// Round 6
// 358.164 us; speedup vs baseline: 1.9749x; 1.9749x over previous
//
#include <hip/hip_runtime.h>

#define DD 1024
#define HALO 32
#define IMG 1088                 // HALO+DD+HALO floats = 17*64 -> swizzle-compatible
#define ROWSTR (2 * IMG)         // floats per row image (both components)
#define HALF_DT_F 0.05f
#define CG_ITERS_N 20

// XOR swizzle on float index (byte' = byte ^ (((byte>>7)&1)<<4)).
// Involution; preserves 16B alignment; commutes with any offset that is a
// multiple of 64 floats (256B): IMG, ROWSTR, +-DD all qualify. Spreads this
// kernel's 32B-lane-stride float4 accesses across all 8 LDS bank groups.
__device__ __forceinline__ int swzf(int f) { return f ^ (((f >> 5) & 1) << 2); }

// Wave64 sum via DPP (pure VALU, ~40-cyc dependent chain vs ~200+ for
// ds_bpermute shuffles). Total valid in lane 63 ONLY.
__device__ __forceinline__ float dpp_wave_sum(float v) {
    int b;
    b = __builtin_amdgcn_update_dpp(0, __float_as_int(v), 0x111, 0xf, 0xf, true); v += __int_as_float(b); // row_shr:1
    b = __builtin_amdgcn_update_dpp(0, __float_as_int(v), 0x112, 0xf, 0xf, true); v += __int_as_float(b); // row_shr:2
    b = __builtin_amdgcn_update_dpp(0, __float_as_int(v), 0x114, 0xf, 0xf, true); v += __int_as_float(b); // row_shr:4
    b = __builtin_amdgcn_update_dpp(0, __float_as_int(v), 0x118, 0xf, 0xf, true); v += __int_as_float(b); // row_shr:8
    b = __builtin_amdgcn_update_dpp(0, __float_as_int(v), 0x142, 0xa, 0xf, true); v += __int_as_float(b); // row_bcast:15
    b = __builtin_amdgcn_update_dpp(0, __float_as_int(v), 0x143, 0xc, 0xf, true); v += __int_as_float(b); // row_bcast:31
    return v;
}

// Row-wide (128-thread, 2-wave) sum; exactly one barrier. Caller alternates
// `red` buffers so consecutive reductions never reuse a live buffer.
__device__ __forceinline__ float row_sum(float v, float* red, int wave, int rw) {
    v = dpp_wave_sum(v);
    if ((threadIdx.x & 63) == 63) red[wave] = v;   // lane 63 holds wave total
    __syncthreads();
    return red[2 * rw] + red[2 * rw + 1];
}

// H on this thread's 8 elements. Window = 48 floats [d0-20, d0+28); the 8
// center values are this thread's own p (passed in regs) -> only 10 b128
// LDS reads per component.
__device__ __forceinline__ void hmat8(const float* lds, const int ra[10], int cOff,
                                      const float cw[11], const float diag[8],
                                      const float pc[8], float H[8]) {
    float win[48];
#pragma unroll
    for (int k = 0; k < 5; ++k) {
        float4 v = *reinterpret_cast<const float4*>(&lds[ra[k] + cOff]);
        win[4 * k + 0] = v.x; win[4 * k + 1] = v.y;
        win[4 * k + 2] = v.z; win[4 * k + 3] = v.w;
    }
#pragma unroll
    for (int i = 0; i < 8; ++i) win[20 + i] = pc[i];
#pragma unroll
    for (int k = 0; k < 5; ++k) {
        float4 v = *reinterpret_cast<const float4*>(&lds[ra[5 + k] + cOff]);
        win[28 + 4 * k + 0] = v.x; win[28 + 4 * k + 1] = v.y;
        win[28 + 4 * k + 2] = v.z; win[28 + 4 * k + 3] = v.w;
    }
    constexpr int taps[11] = {1, 2, 3, 4, 5, 6, 8, 10, 12, 16, 20};
#pragma unroll
    for (int i = 0; i < 8; ++i) {
        float acc = diag[i] * win[20 + i];
#pragma unroll
        for (int j = 0; j < 11; ++j)
            acc -= cw[j] * (win[20 + i - taps[j]] + win[20 + i + taps[j]]);
        H[i] = acc;
    }
}

// Store this thread's 8 elements (both components) + halo copies
// (row-threads 0..3 duplicate to the right halo, 124..127 to the left).
__device__ __forceinline__ void store_row8(float* lds, const int wa[2], const int ha[2],
                                           bool hh, const float vr[8], const float vi[8]) {
#pragma unroll
    for (int j = 0; j < 2; ++j) {
        float4 a = make_float4(vr[4 * j], vr[4 * j + 1], vr[4 * j + 2], vr[4 * j + 3]);
        float4 b = make_float4(vi[4 * j], vi[4 * j + 1], vi[4 * j + 2], vi[4 * j + 3]);
        *reinterpret_cast<float4*>(&lds[wa[j]]) = a;
        *reinterpret_cast<float4*>(&lds[wa[j] + IMG]) = b;
        if (hh) {
            *reinterpret_cast<float4*>(&lds[ha[j]]) = a;
            *reinterpret_cast<float4*>(&lds[ha[j] + IMG]) = b;
        }
    }
}

__global__ void __launch_bounds__(256, 2)
cayley_kernel(const float* __restrict__ psi_r, const float* __restrict__ psi_i,
              const float* __restrict__ alpha, const float* __restrict__ sw,
              const float* __restrict__ potential, float* __restrict__ out) {
    __shared__ __align__(16) float lds[2 * ROWSTR];   // 2 rows x 2 comps
    __shared__ float red0[4], red1[4];

    const int t = threadIdx.x;
    const int u = t & 127;         // row-local thread: owns elements [8u, 8u+8)
    const int rw = t >> 7;         // row within block (0/1)
    const int wave = t >> 6;
    const int rb = rw * ROWSTR;
    const int row = (blockIdx.x << 1) + rw;

    const float w0 = sw[0], w1 = sw[1], w2 = sw[2];   // uniform -> SGPRs
    const float cw[11] = {w0, w0 + w1, w0, w0 + w1 + w2, w0, w1, w1 + w2, w1, w2, w2, w2};
    const float dadd = 10.0f * (w0 + w1 + w2);

    // Loop-invariant swizzled LDS addresses (float indices, component 0).
    int wa[2], ra[10];
#pragma unroll
    for (int j = 0; j < 2; ++j) wa[j] = swzf(rb + HALO + 8 * u + 4 * j);
#pragma unroll
    for (int k = 0; k < 5; ++k) {
        ra[k]     = swzf(rb + HALO + 8 * u - 20 + 4 * k);        // left 20 floats
        ra[5 + k] = swzf(rb + HALO + 8 * u + 8 + 4 * k);         // right 20 floats
    }
    const bool hh = (u < 4) || (u >= 124);
    int ha[2] = {0, 0};
    if (u < 4) {
#pragma unroll
        for (int j = 0; j < 2; ++j) ha[j] = swzf(rb + HALO + 8 * u + DD + 4 * j);
    } else if (u >= 124) {
#pragma unroll
        for (int j = 0; j < 2; ++j) ha[j] = swzf(rb + HALO + 8 * u - DD + 4 * j);
    }

    // --- global loads: 8 contiguous elements per thread ---
    const size_t goff = (size_t)row * DD + 8 * u;
    float prv[8], piv[8], diag[8];
#pragma unroll
    for (int j = 0; j < 2; ++j) {
        float4 a = *reinterpret_cast<const float4*>(psi_r + goff + 4 * j);
        float4 b = *reinterpret_cast<const float4*>(psi_i + goff + 4 * j);
        float4 d = *reinterpret_cast<const float4*>(potential + 8 * u + 4 * j);
        prv[4 * j] = a.x; prv[4 * j + 1] = a.y; prv[4 * j + 2] = a.z; prv[4 * j + 3] = a.w;
        piv[4 * j] = b.x; piv[4 * j + 1] = b.y; piv[4 * j + 2] = b.z; piv[4 * j + 3] = b.w;
        diag[4 * j] = d.x + dadd; diag[4 * j + 1] = d.y + dadd;
        diag[4 * j + 2] = d.z + dadd; diag[4 * j + 3] = d.w + dadd;
    }

    // --- intensity mean over the row ---
    float isum = 0.f;
#pragma unroll
    for (int i = 0; i < 8; ++i) isum += prv[i] * prv[i] + piv[i] * piv[i];
    const float tot = row_sum(isum, red0, wave, rw);
    const float inv_mean = 1.0f / (tot * (1.0f / DD) + 1e-8f);

    // --- nonlinear phase rotation (in place; rot stays in prv/piv) ---
#pragma unroll
    for (int j = 0; j < 2; ++j) {
        float4 c = *reinterpret_cast<const float4*>(alpha + 8 * u + 4 * j);
        float av[4] = {c.x, c.y, c.z, c.w};
#pragma unroll
        for (int q = 0; q < 4; ++q) {
            const int i = 4 * j + q;
            const float ph = av[q] * ((prv[i] * prv[i] + piv[i] * piv[i]) * inv_mean);
            float s, cc;
            __sincosf(ph, &s, &cc);
            const float nr = prv[i] * cc - piv[i] * s;
            const float ni = prv[i] * s + piv[i] * cc;
            prv[i] = nr; piv[i] = ni;
        }
    }

    store_row8(lds, wa, ha, hh, prv, piv);
    __syncthreads();

    // --- rhs = (I - i*dt/2*H) rot ; r = p = rhs ; x = 0 ---
    float Hr[8], Hi[8];
    hmat8(lds, ra, 0, cw, diag, prv, Hr);
    hmat8(lds, ra, IMG, cw, diag, piv, Hi);

    float xr[8], xi[8], rr[8], ri[8], pr_[8], pi_[8];
    float rsum = 0.f;
#pragma unroll
    for (int i = 0; i < 8; ++i) {
        xr[i] = 0.f; xi[i] = 0.f;
        rr[i] = prv[i] + HALF_DT_F * Hi[i];
        ri[i] = piv[i] - HALF_DT_F * Hr[i];
        pr_[i] = rr[i]; pi_[i] = ri[i];
        rsum += rr[i] * rr[i] + ri[i] * ri[i];
    }
    float rs = row_sum(rsum, red1, wave, rw);   // barrier fences hmat reads

    store_row8(lds, wa, ha, hh, pr_, pi_);
    __syncthreads();

    // --- CG: 20 fixed iterations, 3 barriers each ---
#pragma unroll 1
    for (int it = 0; it < CG_ITERS_N; ++it) {
        hmat8(lds, ra, 0, cw, diag, pr_, Hr);
        hmat8(lds, ra, IMG, cw, diag, pi_, Hi);

        // pAp with Ap = (pr - hdt*Hi, pi + hdt*Hr), never materialized.
        float pap = 0.f;
#pragma unroll
        for (int i = 0; i < 8; ++i)
            pap += pr_[i] * pr_[i] + pi_[i] * pi_[i]
                 - HALF_DT_F * (pr_[i] * Hi[i] - pi_[i] * Hr[i]);
        const float pAp = row_sum(pap, red0, wave, rw);   // barrier #1 (fences window reads)
        const float al = rs / (pAp + 1e-12f);
        const float alh = al * HALF_DT_F;

        float rnew = 0.f;
#pragma unroll
        for (int i = 0; i < 8; ++i) {
            xr[i] += al * pr_[i];
            xi[i] += al * pi_[i];
            rr[i] = rr[i] - al * pr_[i] + alh * Hi[i];
            ri[i] = ri[i] - al * pi_[i] - alh * Hr[i];
            rnew += rr[i] * rr[i] + ri[i] * ri[i];
        }
        const float rs_new = row_sum(rnew, red1, wave, rw);   // barrier #2
        const float beta = rs_new / (rs + 1e-12f);
        rs = rs_new;
#pragma unroll
        for (int i = 0; i < 8; ++i) {
            pr_[i] = rr[i] + beta * pr_[i];
            pi_[i] = ri[i] + beta * pi_[i];
        }
        store_row8(lds, wa, ha, hh, pr_, pi_);
        __syncthreads();                                      // barrier #3
    }

    // --- write x as [.., D, 2] real pairs: 8 complex = 4 float4, coalesced ---
    float* op = out + 2 * goff;
#pragma unroll
    for (int j = 0; j < 4; ++j) {
        *reinterpret_cast<float4*>(op + 4 * j) =
            make_float4(xr[2 * j], xi[2 * j], xr[2 * j + 1], xi[2 * j + 1]);
    }
}

extern "C" void kernel_launch(void* const* d_in, const int* in_sizes, int n_in,
                              void* d_out, int out_size, void* d_ws, size_t ws_size,
                              hipStream_t stream) {
    const float* psi_r = (const float*)d_in[0];
    const float* psi_i = (const float*)d_in[1];
    const float* alpha = (const float*)d_in[2];
    const float* sw = (const float*)d_in[3];
    const float* pot = (const float*)d_in[4];
    float* out = (float*)d_out;
    const int rows = in_sizes[0] / DD;   // B*S = 8192
    cayley_kernel<<<dim3(rows / 2), dim3(256), 0, stream>>>(psi_r, psi_i, alpha, sw, pot, out);
}

// Round 7
// 282.551 us; speedup vs baseline: 2.5034x; 1.2676x over previous
//
#include <hip/hip_runtime.h>

#define DD 1024
#define HALO 32
#define IMGF (2 * (HALO + DD + HALO))   // floats per interleaved row image = 2176 = 17*128
#define HALF_DT_F 0.05f
#define CG_ITERS_N 20

typedef float f2 __attribute__((ext_vector_type(2)));   // (re, im) -> v_pk_* ops

// XOR swizzle on float index (byte' = byte ^ (((byte>>7)&3)<<4)).
// Involution; preserves 16B alignment; commutes with any offset that is a
// multiple of 128 floats (512B): IMGF row base and +-2*DD halo shifts qualify.
// For this kernel's 64B-lane-stride float4 accesses, 8 consecutive lanes map
// to 8 distinct 4-bank groups -> conflict-free-optimal for ds_read_b128.
__device__ __forceinline__ int swzf(int f) { return f ^ (((f >> 5) & 3) << 2); }

// Wave64 sum via DPP (pure VALU). Total valid in lane 63 ONLY.
__device__ __forceinline__ float dpp_wave_sum(float v) {
    int b;
    b = __builtin_amdgcn_update_dpp(0, __float_as_int(v), 0x111, 0xf, 0xf, true); v += __int_as_float(b); // row_shr:1
    b = __builtin_amdgcn_update_dpp(0, __float_as_int(v), 0x112, 0xf, 0xf, true); v += __int_as_float(b); // row_shr:2
    b = __builtin_amdgcn_update_dpp(0, __float_as_int(v), 0x114, 0xf, 0xf, true); v += __int_as_float(b); // row_shr:4
    b = __builtin_amdgcn_update_dpp(0, __float_as_int(v), 0x118, 0xf, 0xf, true); v += __int_as_float(b); // row_shr:8
    b = __builtin_amdgcn_update_dpp(0, __float_as_int(v), 0x142, 0xa, 0xf, true); v += __int_as_float(b); // row_bcast:15
    b = __builtin_amdgcn_update_dpp(0, __float_as_int(v), 0x143, 0xc, 0xf, true); v += __int_as_float(b); // row_bcast:31
    return v;
}

// Row-wide (128-thread, 2-wave) sum; exactly one barrier. Caller alternates
// `red` buffers so consecutive reductions never reuse a live buffer.
__device__ __forceinline__ float row_sum(float v, float* red, int wave, int rw) {
    v = dpp_wave_sum(v);
    if ((threadIdx.x & 63) == 63) red[wave] = v;
    __syncthreads();
    return red[2 * rw] + red[2 * rw + 1];
}

// Packed H-apply on this thread's 8 complex elements (center passed in regs).
// Two passes (left 20 neighbors, right 20 neighbors), 10 b128 reads each, so
// at most ~40 window floats are live at once.
__device__ __forceinline__ void hmat8p(const float* lds, const int raL[10], const int raR[10],
                                       const float cw[11], const float diag[8],
                                       const f2 pc[8], f2 H[8]) {
    constexpr int taps[11] = {1, 2, 3, 4, 5, 6, 8, 10, 12, 16, 20};
    {   // ---- pass L: left window [d0-20, d0) + all center-resident taps ----
        f2 lw[20];
#pragma unroll
        for (int k = 0; k < 10; ++k) {
            float4 v = *reinterpret_cast<const float4*>(&lds[raL[k]]);
            lw[2 * k] = f2{v.x, v.y};
            lw[2 * k + 1] = f2{v.z, v.w};
        }
#pragma unroll
        for (int i = 0; i < 8; ++i) {
            f2 acc = diag[i] * pc[i];
#pragma unroll
            for (int j = 0; j < 11; ++j) {
                const int n = i - taps[j];
                const f2 vl = (n >= 0) ? pc[n] : lw[20 + n];
                acc -= cw[j] * vl;
                const int m = i + taps[j];
                if (m <= 7) acc -= cw[j] * pc[m];
            }
            H[i] = acc;
        }
    }
    {   // ---- pass R: right window (d0+7, d0+28) ----
        f2 rw2[20];
#pragma unroll
        for (int k = 0; k < 10; ++k) {
            float4 v = *reinterpret_cast<const float4*>(&lds[raR[k]]);
            rw2[2 * k] = f2{v.x, v.y};
            rw2[2 * k + 1] = f2{v.z, v.w};
        }
#pragma unroll
        for (int i = 0; i < 8; ++i) {
            f2 acc = H[i];
#pragma unroll
            for (int j = 0; j < 11; ++j) {
                const int m = i + taps[j];
                if (m > 7) acc -= cw[j] * rw2[m - 8];
            }
            H[i] = acc;
        }
    }
}

// Store this thread's 8 interleaved complex (4 float4) + halo copies
// (row-threads 0..3 duplicate right, 124..127 left).
__device__ __forceinline__ void store_row8p(float* lds, const int wa[4], const int ha[4],
                                            bool hh, const f2 v[8]) {
#pragma unroll
    for (int j = 0; j < 4; ++j) {
        float4 a = make_float4(v[2 * j].x, v[2 * j].y, v[2 * j + 1].x, v[2 * j + 1].y);
        *reinterpret_cast<float4*>(&lds[wa[j]]) = a;
        if (hh) *reinterpret_cast<float4*>(&lds[ha[j]]) = a;
    }
}

__global__ void __launch_bounds__(256, 2)
cayley_kernel(const float* __restrict__ psi_r, const float* __restrict__ psi_i,
              const float* __restrict__ alpha, const float* __restrict__ sw,
              const float* __restrict__ potential, float* __restrict__ out) {
    __shared__ __align__(16) float lds[2 * IMGF];   // 2 rows, interleaved complex
    __shared__ float red0[4], red1[4];

    const int t = threadIdx.x;
    const int u = t & 127;         // row-local thread: owns complex [8u, 8u+8)
    const int rw = t >> 7;         // row within block (0/1)
    const int wave = t >> 6;
    const int rb = rw * IMGF;
    const int row = (blockIdx.x << 1) + rw;

    const float w0 = sw[0], w1 = sw[1], w2 = sw[2];   // uniform -> SGPRs
    const float cw[11] = {w0, w0 + w1, w0, w0 + w1 + w2, w0, w1, w1 + w2, w1, w2, w2, w2};
    const float dadd = 10.0f * (w0 + w1 + w2);

    // Loop-invariant swizzled LDS float-index addresses.
    const int fb = rb + 2 * (HALO + 8 * u);   // float index of this thread's first complex
    int wa[4], raL[10], raR[10];
#pragma unroll
    for (int j = 0; j < 4; ++j) wa[j] = swzf(fb + 4 * j);
#pragma unroll
    for (int k = 0; k < 10; ++k) {
        raL[k] = swzf(fb - 40 + 4 * k);       // left 20 complex
        raR[k] = swzf(fb + 16 + 4 * k);       // right 20 complex
    }
    const bool hh = (u < 4) || (u >= 124);
    int ha[4] = {0, 0, 0, 0};
    if (u < 4) {
#pragma unroll
        for (int j = 0; j < 4; ++j) ha[j] = swzf(fb + 2 * DD + 4 * j);
    } else if (u >= 124) {
#pragma unroll
        for (int j = 0; j < 4; ++j) ha[j] = swzf(fb - 2 * DD + 4 * j);
    }

    // --- global loads: 8 complex per thread (planar in, packed regs) ---
    const size_t goff = (size_t)row * DD + 8 * u;
    f2 cur[8];           // current field: psi -> rot -> (reused)
    float diag[8];
#pragma unroll
    for (int j = 0; j < 2; ++j) {
        float4 a = *reinterpret_cast<const float4*>(psi_r + goff + 4 * j);
        float4 b = *reinterpret_cast<const float4*>(psi_i + goff + 4 * j);
        float4 d = *reinterpret_cast<const float4*>(potential + 8 * u + 4 * j);
        cur[4 * j + 0] = f2{a.x, b.x};
        cur[4 * j + 1] = f2{a.y, b.y};
        cur[4 * j + 2] = f2{a.z, b.z};
        cur[4 * j + 3] = f2{a.w, b.w};
        diag[4 * j] = d.x + dadd; diag[4 * j + 1] = d.y + dadd;
        diag[4 * j + 2] = d.z + dadd; diag[4 * j + 3] = d.w + dadd;
    }

    // --- intensity mean over the row ---
    float isum = 0.f;
#pragma unroll
    for (int i = 0; i < 8; ++i) isum += cur[i].x * cur[i].x + cur[i].y * cur[i].y;
    const float tot = row_sum(isum, red0, wave, rw);
    const float inv_mean = 1.0f / (tot * (1.0f / DD) + 1e-8f);

    // --- nonlinear phase rotation (in place) ---
#pragma unroll
    for (int j = 0; j < 2; ++j) {
        float4 c = *reinterpret_cast<const float4*>(alpha + 8 * u + 4 * j);
        float av[4] = {c.x, c.y, c.z, c.w};
#pragma unroll
        for (int q = 0; q < 4; ++q) {
            const int i = 4 * j + q;
            const float ph = av[q] * ((cur[i].x * cur[i].x + cur[i].y * cur[i].y) * inv_mean);
            float s, cc;
            __sincosf(ph, &s, &cc);
            cur[i] = f2{cur[i].x * cc - cur[i].y * s, cur[i].x * s + cur[i].y * cc};
        }
    }

    store_row8p(lds, wa, ha, hh, cur);
    __syncthreads();

    // --- rhs = (I - i*h*H) rot ; r = p = rhs ; x = 0 ---
    f2 H2[8];
    hmat8p(lds, raL, raR, cw, diag, cur, H2);

    f2 x2[8], r2[8], p2[8];
    float rsum = 0.f;
#pragma unroll
    for (int i = 0; i < 8; ++i) {
        x2[i] = f2{0.f, 0.f};
        r2[i] = f2{cur[i].x + HALF_DT_F * H2[i].y, cur[i].y - HALF_DT_F * H2[i].x};
        p2[i] = r2[i];
        rsum += r2[i].x * r2[i].x + r2[i].y * r2[i].y;
    }
    float rs = row_sum(rsum, red1, wave, rw);   // barrier fences rot-window reads

    store_row8p(lds, wa, ha, hh, p2);
    __syncthreads();

    // --- CG: 20 fixed iterations, 3 barriers each ---
#pragma unroll 1
    for (int it = 0; it < CG_ITERS_N; ++it) {
        hmat8p(lds, raL, raR, cw, diag, p2, H2);

        // Ap = (pr - h*Hi, pi + h*Hr); packed dot p.Ap
        f2 Ap2[8];
        f2 papv = f2{0.f, 0.f};
#pragma unroll
        for (int i = 0; i < 8; ++i) {
            Ap2[i] = f2{p2[i].x - HALF_DT_F * H2[i].y, p2[i].y + HALF_DT_F * H2[i].x};
            papv += p2[i] * Ap2[i];
        }
        const float pAp = row_sum(papv.x + papv.y, red0, wave, rw);   // barrier #1
        const float al = rs / (pAp + 1e-12f);

        f2 rnv = f2{0.f, 0.f};
#pragma unroll
        for (int i = 0; i < 8; ++i) {
            x2[i] += al * p2[i];
            r2[i] -= al * Ap2[i];
            rnv += r2[i] * r2[i];
        }
        const float rs_new = row_sum(rnv.x + rnv.y, red1, wave, rw);  // barrier #2
        const float beta = rs_new / (rs + 1e-12f);
        rs = rs_new;
#pragma unroll
        for (int i = 0; i < 8; ++i) p2[i] = r2[i] + beta * p2[i];

        store_row8p(lds, wa, ha, hh, p2);
        __syncthreads();                                              // barrier #3
    }

    // --- write x: output layout [.., D, 2] is exactly our packed layout ---
    float* op = out + 2 * goff;
#pragma unroll
    for (int j = 0; j < 4; ++j) {
        *reinterpret_cast<float4*>(op + 4 * j) =
            make_float4(x2[2 * j].x, x2[2 * j].y, x2[2 * j + 1].x, x2[2 * j + 1].y);
    }
}

extern "C" void kernel_launch(void* const* d_in, const int* in_sizes, int n_in,
                              void* d_out, int out_size, void* d_ws, size_t ws_size,
                              hipStream_t stream) {
    const float* psi_r = (const float*)d_in[0];
    const float* psi_i = (const float*)d_in[1];
    const float* alpha = (const float*)d_in[2];
    const float* sw = (const float*)d_in[3];
    const float* pot = (const float*)d_in[4];
    float* out = (float*)d_out;
    const int rows = in_sizes[0] / DD;   // B*S = 8192
    cayley_kernel<<<dim3(rows / 2), dim3(256), 0, stream>>>(psi_r, psi_i, alpha, sw, pot, out);
}